// Round 14
// baseline (158.965 us; speedup 1.0000x reference)
//
#include <hip/hip_runtime.h>

// Problem constants
static constexpr int Bc = 64;     // batch
static constexpr int Nc = 4096;   // set size
static constexpr int Dc = 128;    // d_in
static constexpr int Mc = 1024;   // num ref points
static constexpr int Lc = 128;    // num projections

using short8   = __attribute__((ext_vector_type(8))) short;
using ushort8v = __attribute__((ext_vector_type(8))) unsigned short;
using f32x4    = __attribute__((ext_vector_type(4))) float;
using u32x4    = __attribute__((ext_vector_type(4))) unsigned;

__device__ __forceinline__ unsigned short f2bf(float x) {
  unsigned u = __builtin_bit_cast(unsigned, x);
  return (unsigned short)((u + 0x7FFFu + ((u >> 16) & 1u)) >> 16);
}
__device__ __forceinline__ float bf2f(unsigned short h) {
  unsigned u = ((unsigned)h) << 16;
  return __builtin_bit_cast(float, u);
}

__device__ __forceinline__ int swz(int i) { return i ^ ((i >> 4) & 31); }

// ---------------------------------------------------------------------------
// Kernel 1 (setup): per l-block (128 blocks x 256 threads):
//   - Wh/Wl[l][d] = bf16 hi/lo split of theta_v[l]/||theta_v[l]||
//   - C[l] = sum_m ref[m,l]*weight[l,m]
//   - v[l][n]: binning-rank argsort of ref column + interp stencil scatter
// ---------------------------------------------------------------------------
__global__ __launch_bounds__(256) void setup_kernel(
    const float* __restrict__ theta_v, const float* __restrict__ ref,
    const float* __restrict__ weight, unsigned short* __restrict__ Wh,
    unsigned short* __restrict__ Wl, float* __restrict__ C,
    float* __restrict__ v) {
  constexpr int NBv = 2048;
  constexpr float LOv = -4.2f;
  constexpr float SCv = (float)NBv / 8.4f;

  __shared__ int pref[NBv];            // 8 KB
  __shared__ float skey[Mc];           // 4 KB
  __shared__ unsigned short sidx[Mc];  // 2 KB
  __shared__ float vrow[Nc];           // 16 KB
  __shared__ int wsum[4];
  __shared__ float s2[2];
  __shared__ float c4[4];

  int l = blockIdx.x;
  int tid = threadIdx.x;
  int lane = tid & 63, wv = tid >> 6;

  // ref column (also reused for C)
  float x[4];
  #pragma unroll
  for (int j = 0; j < 4; ++j) x[j] = ref[(size_t)(tid + 256 * j) * Lc + l];

  for (int i = tid; i < NBv; i += 256) pref[i] = 0;
  for (int i = tid; i < Nc; i += 256) vrow[i] = 0.f;

  // W-norm partial (threads 0..127; waves 0,1)
  float wval = 0.f;
  if (tid < Dc) {
    wval = theta_v[l * Dc + tid];
    float sq = wval * wval;
    #pragma unroll
    for (int off = 1; off < 64; off <<= 1) sq += __shfl_xor(sq, off, 64);
    if (lane == 0) s2[wv] = sq;
  }
  // C partial (all threads, reuses x)
  {
    float cacc = 0.f;
    #pragma unroll
    for (int j = 0; j < 4; ++j) cacc += x[j] * weight[(size_t)l * Mc + tid + 256 * j];
    #pragma unroll
    for (int off = 1; off < 64; off <<= 1) cacc += __shfl_xor(cacc, off, 64);
    if (lane == 0) c4[wv] = cacc;
  }
  __syncthreads();

  if (tid < Dc) {
    float norm = sqrtf(s2[0] + s2[1]);
    float val = wval / norm;
    unsigned short hi = f2bf(val);
    Wh[l * Dc + tid] = hi;
    Wl[l * Dc + tid] = f2bf(val - bf2f(hi));
  }
  if (tid == 0) C[l] = c4[0] + c4[1] + c4[2] + c4[3];

  // histogram
  int bb[4];
  #pragma unroll
  for (int j = 0; j < 4; ++j) {
    int bi = (int)((x[j] - LOv) * SCv);
    bi = bi < 0 ? 0 : (bi > NBv - 1 ? NBv - 1 : bi);
    bb[j] = bi;
    atomicAdd(&pref[swz(bi)], 1);
  }
  __syncthreads();

  // exclusive prefix over 2048 bins (8/thread)
  {
    int base_ = tid * 8;
    int loc[8]; int s = 0;
    #pragma unroll
    for (int j = 0; j < 8; ++j) loc[j] = pref[swz(base_ + j)];
    #pragma unroll
    for (int j = 0; j < 8; ++j) { int c = loc[j]; loc[j] = s; s += c; }
    int inc = s;
    #pragma unroll
    for (int off = 1; off < 64; off <<= 1) {
      int o = __shfl_up(inc, off, 64);
      if (lane >= off) inc += o;
    }
    if (lane == 63) wsum[wv] = inc;
    __syncthreads();
    int wbase = 0;
    #pragma unroll
    for (int ww = 0; ww < 4; ++ww) if (ww < wv) wbase += wsum[ww];
    int tbase = wbase + inc - s;
    #pragma unroll
    for (int j = 0; j < 8; ++j) pref[swz(base_ + j)] = tbase + loc[j];
  }
  __syncthreads();

  // scatter (value, orig idx)
  #pragma unroll
  for (int j = 0; j < 4; ++j) {
    int p = atomicAdd(&pref[swz(bb[j])], 1);
    skey[p] = x[j];
    sidx[p] = (unsigned short)(tid + 256 * j);
  }
  __syncthreads();

  // position-ordered exact rank (stable: (value, orig idx)) + stencil scatter
  #pragma unroll
  for (int k = 0; k < 4; ++k) {
    int p = tid + 256 * k;
    float y = skey[p];
    int m = sidx[p];
    int b = (int)((y - LOv) * SCv);
    b = b < 0 ? 0 : (b > NBv - 1 ? NBv - 1 : b);
    int lo_ = b ? pref[swz(b - 1)] : 0;
    int hi_ = pref[swz(b)];
    int r = lo_;
    for (int q = lo_; q < hi_; ++q) {
      float z = skey[q];
      r += (z < y || (z == y && sidx[q] < m)) ? 1 : 0;
    }
    // element with original index m has rank r in the stable argsort
    float wvv = weight[(size_t)l * Mc + r];
    double pos = (double)(m + 1) * (double)(Nc + 1) / (double)(Mc + 1) - 1.0;
    int i0 = (int)pos;
    float t = (float)(pos - (double)i0);
    atomicAdd(&vrow[i0], (1.0f - t) * wvv);
    atomicAdd(&vrow[i0 + 1], t * wvv);
  }
  __syncthreads();
  for (int i = tid; i < Nc; i += 256) v[(size_t)l * Nc + i] = vrow[i];
}

// ---------------------------------------------------------------------------
// Kernel 2: MFMA GEMM, f32 = bf16 hi + lo (3-term). OUTPUT: bf16 (u16).
//  512 threads = 8 waves; wave wv owns 16 n-rows x 128 l.
//  A: lane loads its row-slices once up-front (coalesced), converts per
//  chunk in-register. B: double-buffered LDS; one barrier per chunk.
// sl16[bloc][l][n] = bf16( sum_d X[bloc,n,d] * W[l,d] )
// ---------------------------------------------------------------------------
__global__ __launch_bounds__(512) void gemm_kernel(
    const float* __restrict__ X, const unsigned short* __restrict__ Whp,
    const unsigned short* __restrict__ Wlp, unsigned short* __restrict__ sl) {
  __shared__ unsigned short Bh[2][128][40];  // 20 KB
  __shared__ unsigned short Bl[2][128][40];  // 20 KB

  int bloc = blockIdx.y;
  int nbase = blockIdx.x * 128;
  int tid = threadIdx.x;
  int lane = tid & 63;
  int wv = tid >> 6;       // wave 0..7 -> 16 n-rows each
  int m16 = lane & 15;
  int kg = lane >> 4;

  // B staging: one 8-u16 segment per thread per array
  int brow = tid >> 2;
  int bc = (tid & 3) * 8;
  const unsigned short* gbh = Whp + (size_t)brow * Dc + bc;
  const unsigned short* gbl = Wlp + (size_t)brow * Dc + bc;

  // ---- A: full kg-slice of the lane's row, all 4 chunks, up-front
  const float* arow = X + ((size_t)bloc * Nc + nbase + wv * 16 + m16) * Dc + kg * 8;
  float4 af[4][2];
  #pragma unroll
  for (int c = 0; c < 4; ++c) {
    af[c][0] = *(const float4*)(arow + c * 32);
    af[c][1] = *(const float4*)(arow + c * 32 + 4);
  }

  // prologue: B chunk 0 -> buf0; B chunk 1 -> regs
  ushort8v rbh = *(const ushort8v*)gbh;
  ushort8v rbl = *(const ushort8v*)gbl;
  *(ushort8v*)&Bh[0][brow][bc] = rbh;
  *(ushort8v*)&Bl[0][brow][bc] = rbl;
  rbh = *(const ushort8v*)(gbh + 32);
  rbl = *(const ushort8v*)(gbl + 32);

  f32x4 acc[8] = {};
  __syncthreads();  // buf0 visible

  #pragma unroll
  for (int c = 0; c < 4; ++c) {
    if (c < 3) {
      *(ushort8v*)&Bh[(c + 1) & 1][brow][bc] = rbh;
      *(ushort8v*)&Bl[(c + 1) & 1][brow][bc] = rbl;
    }
    if (c < 2) {
      rbh = *(const ushort8v*)(gbh + (c + 2) * 32);
      rbl = *(const ushort8v*)(gbl + (c + 2) * 32);
    }

    // convert A chunk c
    float xs[8] = {af[c][0].x, af[c][0].y, af[c][0].z, af[c][0].w,
                   af[c][1].x, af[c][1].y, af[c][1].z, af[c][1].w};
    short8 ah, al;
    #pragma unroll
    for (int e = 0; e < 8; ++e) {
      unsigned short h = f2bf(xs[e]);
      ah[e] = (short)h;
      al[e] = (short)f2bf(xs[e] - bf2f(h));
    }

    #pragma unroll
    for (int u = 0; u < 8; ++u) {
      short8 bh = *(const short8*)&Bh[c & 1][u * 16 + m16][kg * 8];
      short8 bl = *(const short8*)&Bl[c & 1][u * 16 + m16][kg * 8];
      acc[u] = __builtin_amdgcn_mfma_f32_16x16x32_bf16(ah, bh, acc[u], 0, 0, 0);
      acc[u] = __builtin_amdgcn_mfma_f32_16x16x32_bf16(ah, bl, acc[u], 0, 0, 0);
      acc[u] = __builtin_amdgcn_mfma_f32_16x16x32_bf16(al, bh, acc[u], 0, 0, 0);
    }
    __syncthreads();
  }

  // write-out as bf16: C/D col = m16 (l), row = kg*4 + reg (n)
  #pragma unroll
  for (int u = 0; u < 8; ++u) {
    int l = u * 16 + m16;
    int n0 = nbase + wv * 16 + kg * 4;
    unsigned short* dst = sl + ((size_t)bloc * Lc + l) * Nc + n0;
    ushort4 o;
    o.x = f2bf(acc[u][0]); o.y = f2bf(acc[u][1]);
    o.z = f2bf(acc[u][2]); o.w = f2bf(acc[u][3]);
    *(ushort4*)dst = o;
  }
}

// ---------------------------------------------------------------------------
// Kernel 3 (v11): packed-cell radix-rank + fused dot, 512 threads.
//  - slices arrive as bf16; monotone u16 key = bits^(sign?0xFFFF:0x8000)
//  - scatter writes ONE u32 cell = (bin<<16)|key at the binned position
//  - rank predicate = single u32 compare (bin in high bits makes cross-bin
//    ordering automatic): r += (z<yc) + (z==yc && q<p). 4 cells/ds_read_b128.
//  - ties are bitwise-equal bf16 values -> rank-set per tie group fixed,
//    same y -> dot deterministic regardless of atomic arrival order.
//  LDS = pref 16K + cell 16K = 32 KB.
// ---------------------------------------------------------------------------
__device__ __forceinline__ int gbin(float x) {
  constexpr int NB = 4096;
  // NB / (1 + exp(-1.702 x)) = NB / (1 + exp2(-2.45541 x))  (monotone)
  float t = __builtin_amdgcn_exp2f(x * -2.45541f);
  float r = __builtin_amdgcn_rcpf(1.0f + t);
  int bi = (int)((float)NB * r);
  return bi < 0 ? 0 : (bi > NB - 1 ? NB - 1 : bi);
}

__global__ __launch_bounds__(512, 8) void rank_dot_kernel(
    const unsigned short* __restrict__ sl, const float* __restrict__ v,
    const float* __restrict__ C, float* __restrict__ out, int b0) {
  constexpr int NB = 4096;
  constexpr int NT = 512;
  constexpr int EL = Nc / NT;  // 8 elements per thread

  __shared__ int pref[NB];                    // hist -> EXCLUSIVE prefix; then red
  __shared__ __align__(16) unsigned cell[Nc]; // (wsum during scan) packed cells
  int* wsum = (int*)cell;        // live only during scan (before cell writes)
  float* red = (float*)pref;     // live only after final barrier

  int l = blockIdx.x & (Lc - 1);
  int bloc = blockIdx.x >> 7;
  int tid = threadIdx.x;
  const unsigned short* src = sl + ((size_t)bloc * Lc + l) * Nc;

  // one b128 load: thread owns 8 consecutive bf16 elements
  ushort8v kv = *(const ushort8v*)(src + (size_t)tid * 8);
  float x[EL];
  unsigned mk[EL];
  #pragma unroll
  for (int j = 0; j < EL; ++j) {
    unsigned short u = (unsigned short)kv[j];
    x[j] = bf2f(u);
    mk[j] = (u & 0x8000u) ? (unsigned)(u ^ 0xFFFFu) : (unsigned)(u | 0x8000u);
  }

  // zero pref via 2x b128 per thread
  {
    int4 z = make_int4(0, 0, 0, 0);
    ((int4*)pref)[tid] = z;
    ((int4*)pref)[tid + NT] = z;
  }
  __syncthreads();

  // histogram; returned old count = within-bin slot
  int bb[EL];
  int ofs[EL];
  #pragma unroll
  for (int j = 0; j < EL; ++j) {
    int bi = gbin(x[j]);
    bb[j] = bi;
    ofs[j] = atomicAdd(&pref[swz(bi)], 1);
  }
  __syncthreads();

  // exclusive prefix sum over 4096 bins (8 bins/thread)
  {
    int base_ = tid * 8;
    int loc[8]; int s = 0;
    #pragma unroll
    for (int j = 0; j < 8; ++j) loc[j] = pref[swz(base_ + j)];
    #pragma unroll
    for (int j = 0; j < 8; ++j) { int c = loc[j]; loc[j] = s; s += c; }
    int lane = tid & 63, wvv = tid >> 6;
    int inc = s;
    #pragma unroll
    for (int off = 1; off < 64; off <<= 1) {
      int o = __shfl_up(inc, off, 64);
      if (lane >= off) inc += o;
    }
    if (lane == 63) wsum[wvv] = inc;
    __syncthreads();
    int wbase = 0;
    #pragma unroll
    for (int ww = 0; ww < 8; ++ww) if (ww < wvv) wbase += wsum[ww];
    int tbase = wbase + inc - s;  // exclusive across threads
    #pragma unroll
    for (int j = 0; j < 8; ++j) pref[swz(base_ + j)] = tbase + loc[j];
  }
  __syncthreads();

  // scatter packed cells: pos = exclusive-prefix + slot (pref unchanged)
  #pragma unroll
  for (int j = 0; j < EL; ++j) {
    int pos = pref[swz(bb[j])] + ofs[j];
    cell[pos] = ((unsigned)bb[j] << 16) | mk[j];
  }
  __syncthreads();

  // POSITION-ORDERED rank + fused dot over aligned u32x4 cell blocks.
  // Cells in earlier bins compare < yc automatically (bin is in the high
  // bits); alignment slack before lo is compensated by starting r at the
  // aligned base. Tie-break q<p within equal cells: bijective; equal cells
  // are bitwise-equal values -> dot sum deterministic.
  const u32x4* cell4 = (const u32x4*)cell;
  const float* vrow = v + (size_t)l * Nc;
  float acc = 0.f;
  #pragma unroll
  for (int k = 0; k < EL; ++k) {
    int p = tid + NT * k;
    unsigned yc = cell[p];
    int b = (int)(yc >> 16);
    int lo_ = pref[swz(b)];
    int hi_ = (b == NB - 1) ? Nc : pref[swz(b + 1)];
    int q4 = lo_ >> 2;
    int e4 = (hi_ + 3) >> 2;
    int r = q4 << 2;
    for (; q4 < e4; ++q4) {
      u32x4 z = cell4[q4];
      int qb = q4 << 2;
      r += (z[0] < yc || (z[0] == yc && qb + 0 < p)) ? 1 : 0;
      r += (z[1] < yc || (z[1] == yc && qb + 1 < p)) ? 1 : 0;
      r += (z[2] < yc || (z[2] == yc && qb + 2 < p)) ? 1 : 0;
      r += (z[3] < yc || (z[3] == yc && qb + 3 < p)) ? 1 : 0;
    }
    // reconstruct bf16 value from monotone key
    unsigned short k16 = (unsigned short)(yc & 0xFFFFu);
    unsigned short ub = (k16 & 0x8000u) ? (unsigned short)(k16 ^ 0x8000u)
                                        : (unsigned short)(k16 ^ 0xFFFFu);
    acc += bf2f(ub) * vrow[r];
  }

  #pragma unroll
  for (int off = 1; off < 64; off <<= 1) acc += __shfl_xor(acc, off, 64);
  __syncthreads();  // all pref reads done before red (aliased) is written
  if ((tid & 63) == 0) red[tid >> 6] = acc;
  __syncthreads();
  if (tid == 0) {
    float t = 0.f;
    #pragma unroll
    for (int ww = 0; ww < 8; ++ww) t += red[ww];
    int b = b0 + bloc;
    out[(size_t)b * Lc + l] = C[l] - t;
  }
}

// ---------------------------------------------------------------------------
extern "C" void kernel_launch(void* const* d_in, const int* in_sizes, int n_in,
                              void* d_out, int out_size, void* d_ws, size_t ws_size,
                              hipStream_t stream) {
  const float* X       = (const float*)d_in[0];  // [B,N,D]
  const float* theta_v = (const float*)d_in[1];  // [L,D]
  const float* ref     = (const float*)d_in[2];  // [M,L]
  const float* weight  = (const float*)d_in[3];  // [L,M]
  float* out = (float*)d_out;                    // [B,L]

  // workspace layout: v [L*N] f32 | Wh,Wl [L*D] u16 | C [128] f32 | sl16
  float* v  = (float*)d_ws;
  unsigned short* Wh = (unsigned short*)(v + (size_t)Lc * Nc);
  unsigned short* Wl = Wh + (size_t)Lc * Dc;
  float* Cc = (float*)(Wl + (size_t)Lc * Dc);
  unsigned short* sl = (unsigned short*)(Cc + 128);
  size_t used = (size_t)((char*)sl - (char*)d_ws);
  size_t per_b = (size_t)Lc * Nc * sizeof(unsigned short);  // 1 MB per batch elem
  int chunk = 1;
  if (ws_size > used + per_b) {
    size_t c = (ws_size - used) / per_b;
    chunk = (int)(c > (size_t)Bc ? (size_t)Bc : c);
    if (chunk < 1) chunk = 1;
  }

  setup_kernel<<<Lc, 256, 0, stream>>>(theta_v, ref, weight, Wh, Wl, Cc, v);

  for (int b0 = 0; b0 < Bc; b0 += chunk) {
    int nb = (Bc - b0) < chunk ? (Bc - b0) : chunk;
    dim3 g1(Nc / 128, nb);
    gemm_kernel<<<g1, 512, 0, stream>>>(X + (size_t)b0 * Nc * Dc, Wh, Wl, sl);
    rank_dot_kernel<<<(size_t)nb * Lc, 512, 0, stream>>>(sl, v, Cc, out, b0);
  }
}

// Round 15
// 150.330 us; speedup vs baseline: 1.0574x; 1.0574x over previous
//
#include <hip/hip_runtime.h>
#include <math.h>

// Problem constants
static constexpr int Bc = 64;     // batch
static constexpr int Nc = 4096;   // set size
static constexpr int Dc = 128;    // d_in
static constexpr int Mc = 1024;   // num ref points
static constexpr int Lc = 128;    // num projections

using short8   = __attribute__((ext_vector_type(8))) short;
using ushort8v = __attribute__((ext_vector_type(8))) unsigned short;
using f32x4    = __attribute__((ext_vector_type(4))) float;

__device__ __forceinline__ unsigned short f2bf(float x) {
  unsigned u = __builtin_bit_cast(unsigned, x);
  return (unsigned short)((u + 0x7FFFu + ((u >> 16) & 1u)) >> 16);
}
__device__ __forceinline__ float bf2f(unsigned short h) {
  unsigned u = ((unsigned)h) << 16;
  return __builtin_bit_cast(float, u);
}

__device__ __forceinline__ int swz(int i) { return i ^ ((i >> 4) & 31); }

// ---------------------------------------------------------------------------
// Kernel 1 (setup): per l-block (128 blocks x 256 threads):
//   - Wh/Wl[l][d] = bf16 hi/lo split of theta_v[l]/||theta_v[l]||
//   - C[l] = sum_m ref[m,l]*weight[l,m]
//   - v[l][n]: binning-rank argsort of ref column + interp stencil scatter
// ---------------------------------------------------------------------------
__global__ __launch_bounds__(256) void setup_kernel(
    const float* __restrict__ theta_v, const float* __restrict__ ref,
    const float* __restrict__ weight, unsigned short* __restrict__ Wh,
    unsigned short* __restrict__ Wl, float* __restrict__ C,
    float* __restrict__ v) {
  constexpr int NBv = 2048;
  constexpr float LOv = -4.2f;
  constexpr float SCv = (float)NBv / 8.4f;

  __shared__ int pref[NBv];            // 8 KB
  __shared__ float skey[Mc];           // 4 KB
  __shared__ unsigned short sidx[Mc];  // 2 KB
  __shared__ float vrow[Nc];           // 16 KB
  __shared__ int wsum[4];
  __shared__ float s2[2];
  __shared__ float c4[4];

  int l = blockIdx.x;
  int tid = threadIdx.x;
  int lane = tid & 63, wv = tid >> 6;

  // ref column (also reused for C)
  float x[4];
  #pragma unroll
  for (int j = 0; j < 4; ++j) x[j] = ref[(size_t)(tid + 256 * j) * Lc + l];

  for (int i = tid; i < NBv; i += 256) pref[i] = 0;
  for (int i = tid; i < Nc; i += 256) vrow[i] = 0.f;

  // W-norm partial (threads 0..127; waves 0,1)
  float wval = 0.f;
  if (tid < Dc) {
    wval = theta_v[l * Dc + tid];
    float sq = wval * wval;
    #pragma unroll
    for (int off = 1; off < 64; off <<= 1) sq += __shfl_xor(sq, off, 64);
    if (lane == 0) s2[wv] = sq;
  }
  // C partial (all threads, reuses x)
  {
    float cacc = 0.f;
    #pragma unroll
    for (int j = 0; j < 4; ++j) cacc += x[j] * weight[(size_t)l * Mc + tid + 256 * j];
    #pragma unroll
    for (int off = 1; off < 64; off <<= 1) cacc += __shfl_xor(cacc, off, 64);
    if (lane == 0) c4[wv] = cacc;
  }
  __syncthreads();

  if (tid < Dc) {
    float norm = sqrtf(s2[0] + s2[1]);
    float val = wval / norm;
    unsigned short hi = f2bf(val);
    Wh[l * Dc + tid] = hi;
    Wl[l * Dc + tid] = f2bf(val - bf2f(hi));
  }
  if (tid == 0) C[l] = c4[0] + c4[1] + c4[2] + c4[3];

  // histogram
  int bb[4];
  #pragma unroll
  for (int j = 0; j < 4; ++j) {
    int bi = (int)((x[j] - LOv) * SCv);
    bi = bi < 0 ? 0 : (bi > NBv - 1 ? NBv - 1 : bi);
    bb[j] = bi;
    atomicAdd(&pref[swz(bi)], 1);
  }
  __syncthreads();

  // exclusive prefix over 2048 bins (8/thread)
  {
    int base_ = tid * 8;
    int loc[8]; int s = 0;
    #pragma unroll
    for (int j = 0; j < 8; ++j) loc[j] = pref[swz(base_ + j)];
    #pragma unroll
    for (int j = 0; j < 8; ++j) { int c = loc[j]; loc[j] = s; s += c; }
    int inc = s;
    #pragma unroll
    for (int off = 1; off < 64; off <<= 1) {
      int o = __shfl_up(inc, off, 64);
      if (lane >= off) inc += o;
    }
    if (lane == 63) wsum[wv] = inc;
    __syncthreads();
    int wbase = 0;
    #pragma unroll
    for (int ww = 0; ww < 4; ++ww) if (ww < wv) wbase += wsum[ww];
    int tbase = wbase + inc - s;
    #pragma unroll
    for (int j = 0; j < 8; ++j) pref[swz(base_ + j)] = tbase + loc[j];
  }
  __syncthreads();

  // scatter (value, orig idx)
  #pragma unroll
  for (int j = 0; j < 4; ++j) {
    int p = atomicAdd(&pref[swz(bb[j])], 1);
    skey[p] = x[j];
    sidx[p] = (unsigned short)(tid + 256 * j);
  }
  __syncthreads();

  // position-ordered exact rank (stable: (value, orig idx)) + stencil scatter
  #pragma unroll
  for (int k = 0; k < 4; ++k) {
    int p = tid + 256 * k;
    float y = skey[p];
    int m = sidx[p];
    int b = (int)((y - LOv) * SCv);
    b = b < 0 ? 0 : (b > NBv - 1 ? NBv - 1 : b);
    int lo_ = b ? pref[swz(b - 1)] : 0;
    int hi_ = pref[swz(b)];
    int r = lo_;
    for (int q = lo_; q < hi_; ++q) {
      float z = skey[q];
      r += (z < y || (z == y && sidx[q] < m)) ? 1 : 0;
    }
    // element with original index m has rank r in the stable argsort
    float wvv = weight[(size_t)l * Mc + r];
    double pos = (double)(m + 1) * (double)(Nc + 1) / (double)(Mc + 1) - 1.0;
    int i0 = (int)pos;
    float t = (float)(pos - (double)i0);
    atomicAdd(&vrow[i0], (1.0f - t) * wvv);
    atomicAdd(&vrow[i0 + 1], t * wvv);
  }
  __syncthreads();
  for (int i = tid; i < Nc; i += 256) v[(size_t)l * Nc + i] = vrow[i];
}

// ---------------------------------------------------------------------------
// Kernel 2: MFMA GEMM, f32 = bf16 hi + lo (3-term). f32 output.
//  512 threads = 8 waves; wave wv owns 16 n-rows x 128 l.
// sl[bloc][l][n] = sum_d X[bloc,n,d] * W[l,d]
// ---------------------------------------------------------------------------
__global__ __launch_bounds__(512) void gemm_kernel(
    const float* __restrict__ X, const unsigned short* __restrict__ Whp,
    const unsigned short* __restrict__ Wlp, float* __restrict__ sl) {
  __shared__ unsigned short Bh[2][128][40];  // 20 KB
  __shared__ unsigned short Bl[2][128][40];  // 20 KB

  int bloc = blockIdx.y;
  int nbase = blockIdx.x * 128;
  int tid = threadIdx.x;
  int lane = tid & 63;
  int wv = tid >> 6;       // wave 0..7 -> 16 n-rows each
  int m16 = lane & 15;
  int kg = lane >> 4;

  // B staging: one 8-u16 segment per thread per array
  int brow = tid >> 2;
  int bc = (tid & 3) * 8;
  const unsigned short* gbh = Whp + (size_t)brow * Dc + bc;
  const unsigned short* gbl = Wlp + (size_t)brow * Dc + bc;

  // ---- A: full kg-slice of the lane's row, all 4 chunks, up-front
  const float* arow = X + ((size_t)bloc * Nc + nbase + wv * 16 + m16) * Dc + kg * 8;
  float4 af[4][2];
  #pragma unroll
  for (int c = 0; c < 4; ++c) {
    af[c][0] = *(const float4*)(arow + c * 32);
    af[c][1] = *(const float4*)(arow + c * 32 + 4);
  }

  // prologue: B chunk 0 -> buf0; B chunk 1 -> regs
  ushort8v rbh = *(const ushort8v*)gbh;
  ushort8v rbl = *(const ushort8v*)gbl;
  *(ushort8v*)&Bh[0][brow][bc] = rbh;
  *(ushort8v*)&Bl[0][brow][bc] = rbl;
  rbh = *(const ushort8v*)(gbh + 32);
  rbl = *(const ushort8v*)(gbl + 32);

  f32x4 acc[8] = {};
  __syncthreads();  // buf0 visible

  #pragma unroll
  for (int c = 0; c < 4; ++c) {
    if (c < 3) {
      *(ushort8v*)&Bh[(c + 1) & 1][brow][bc] = rbh;
      *(ushort8v*)&Bl[(c + 1) & 1][brow][bc] = rbl;
    }
    if (c < 2) {
      rbh = *(const ushort8v*)(gbh + (c + 2) * 32);
      rbl = *(const ushort8v*)(gbl + (c + 2) * 32);
    }

    // convert A chunk c
    float xs[8] = {af[c][0].x, af[c][0].y, af[c][0].z, af[c][0].w,
                   af[c][1].x, af[c][1].y, af[c][1].z, af[c][1].w};
    short8 ah, al;
    #pragma unroll
    for (int e = 0; e < 8; ++e) {
      unsigned short h = f2bf(xs[e]);
      ah[e] = (short)h;
      al[e] = (short)f2bf(xs[e] - bf2f(h));
    }

    #pragma unroll
    for (int u = 0; u < 8; ++u) {
      short8 bh = *(const short8*)&Bh[c & 1][u * 16 + m16][kg * 8];
      short8 bl = *(const short8*)&Bl[c & 1][u * 16 + m16][kg * 8];
      acc[u] = __builtin_amdgcn_mfma_f32_16x16x32_bf16(ah, bh, acc[u], 0, 0, 0);
      acc[u] = __builtin_amdgcn_mfma_f32_16x16x32_bf16(ah, bl, acc[u], 0, 0, 0);
      acc[u] = __builtin_amdgcn_mfma_f32_16x16x32_bf16(al, bh, acc[u], 0, 0, 0);
    }
    __syncthreads();
  }

  // write-out: C/D col = m16 (l), row = kg*4 + reg (n)
  #pragma unroll
  for (int u = 0; u < 8; ++u) {
    int l = u * 16 + m16;
    int n0 = nbase + wv * 16 + kg * 4;
    float* dst = sl + ((size_t)bloc * Lc + l) * Nc + n0;
    *(float4*)dst = *(float4*)&acc[u];
  }
}

// ---------------------------------------------------------------------------
// Kernel 3 (v12): radix-bin + FIXED-WINDOW rank + fused dot, 512 threads.
//  If every bin count c <= 8 (P(violation) ~ 0.5% per block, guarded), the
//  exact stable rank of position p is computable from the 20 cells in the
//  5 aligned float4 blocks around p:
//     r(p) = 4*(p>>2) - 8 + sum_s pred_s,
//  pred = (q<p) ? (z<=y) : (q>p) ? (z<y) : 0; cells below the window are in
//  earlier bins (auto z<y, counted via base), above in later bins (auto not).
//  Positions are processed in PAIRS (p0=2t, p1=p0+1) sharing one window:
//  2.5 ds_read_b128 per element, zero loops, zero divergence, no gbin/pref.
//  +-INF sentinels pad skey; q-p sign is compile-time for 16/20 slots (the
//  rest select on one per-thread bool). Overflow -> block-uniform fallback.
// ---------------------------------------------------------------------------
__device__ __forceinline__ int gbin(float x) {
  constexpr int NB = 4096;
  // NB / (1 + exp(-1.702 x)) = NB / (1 + exp2(-2.45541 x))  (monotone)
  float t = __builtin_amdgcn_exp2f(x * -2.45541f);
  float r = __builtin_amdgcn_rcpf(1.0f + t);
  int bi = (int)((float)NB * r);
  return bi < 0 ? 0 : (bi > NB - 1 ? NB - 1 : bi);
}

__global__ __launch_bounds__(512, 8) void rank_dot_kernel(
    const float* __restrict__ sl, const float* __restrict__ v,
    const float* __restrict__ C, float* __restrict__ out, int b0) {
  constexpr int NB = 4096;
  constexpr int NT = 512;
  constexpr int EL = Nc / NT;  // 8 elements per thread

  __shared__ int pref[NB];                        // hist -> EXCLUSIVE prefix; then red
  __shared__ __align__(16) float skey[Nc + 16];   // 8 sentinel floats each side
  __shared__ int wsum[8];
  __shared__ int ovf;
  float* red = (float*)pref;     // live only after final barrier
  float* sk = skey + 8;          // real positions 0..Nc-1

  int l = blockIdx.x & (Lc - 1);
  int bloc = blockIdx.x >> 7;
  int tid = threadIdx.x;
  const float* src = sl + ((size_t)bloc * Lc + l) * Nc;

  // coalesced strided load: thread owns float4s {tid + 512*j}
  float x[EL];
  {
    const float4* s4 = (const float4*)src;
    #pragma unroll
    for (int j = 0; j < EL / 4; ++j) {
      float4 f = s4[tid + NT * j];
      x[j * 4 + 0] = f.x; x[j * 4 + 1] = f.y;
      x[j * 4 + 2] = f.z; x[j * 4 + 3] = f.w;
    }
  }

  // init: zero pref (b128), sentinels, ovf
  {
    int4 z = make_int4(0, 0, 0, 0);
    ((int4*)pref)[tid] = z;
    ((int4*)pref)[tid + NT] = z;
  }
  if (tid < 8) skey[tid] = -INFINITY;
  else if (tid < 16) skey[Nc + tid] = INFINITY;  // indices Nc+8 .. Nc+15
  if (tid == 16) ovf = 0;
  __syncthreads();

  // histogram; returned old count = within-bin slot; slot>=8 -> bin c>=9
  int bb[EL];
  int ofs[EL];
  bool myovf = false;
  #pragma unroll
  for (int j = 0; j < EL; ++j) {
    int bi = gbin(x[j]);
    bb[j] = bi;
    ofs[j] = atomicAdd(&pref[swz(bi)], 1);
    myovf |= (ofs[j] >= 8);
  }
  if (myovf) ovf = 1;
  __syncthreads();

  // exclusive prefix sum over 4096 bins (8 bins/thread)
  {
    int base_ = tid * 8;
    int loc[8]; int s = 0;
    #pragma unroll
    for (int j = 0; j < 8; ++j) loc[j] = pref[swz(base_ + j)];
    #pragma unroll
    for (int j = 0; j < 8; ++j) { int c = loc[j]; loc[j] = s; s += c; }
    int lane = tid & 63, wvv = tid >> 6;
    int inc = s;
    #pragma unroll
    for (int off = 1; off < 64; off <<= 1) {
      int o = __shfl_up(inc, off, 64);
      if (lane >= off) inc += o;
    }
    if (lane == 63) wsum[wvv] = inc;
    __syncthreads();
    int wbase = 0;
    #pragma unroll
    for (int ww = 0; ww < 8; ++ww) if (ww < wvv) wbase += wsum[ww];
    int tbase = wbase + inc - s;  // exclusive across threads
    #pragma unroll
    for (int j = 0; j < 8; ++j) pref[swz(base_ + j)] = tbase + loc[j];
  }
  __syncthreads();

  // scatter: pos = exclusive-prefix + slot (no second atomic; pref unchanged)
  #pragma unroll
  for (int j = 0; j < EL; ++j) {
    sk[pref[swz(bb[j])] + ofs[j]] = x[j];
  }
  __syncthreads();

  const float* vrow = v + (size_t)l * Nc;
  float acc = 0.f;

  if (__builtin_expect(ovf == 0, 1)) {
    // FAST PATH: fixed-window rank, position pairs p0=2t, p1=p0+1.
    // Padded block pb covers real positions [4*pb-8, 4*pb-5].
    const f32x4* sk4 = (const f32x4*)skey;
    bool odd = (tid & 1);  // p0&3 = 2*odd (constant across k since 512k even)
    #pragma unroll
    for (int k = 0; k < 4; ++k) {
      int t = tid + NT * k;     // pair index 0..2047
      int pb0 = t >> 1;         // = p0>>2, p0 = 2t
      f32x4 z0 = sk4[pb0 + 0];
      f32x4 z1 = sk4[pb0 + 1];
      f32x4 z2 = sk4[pb0 + 2];
      f32x4 z3 = sk4[pb0 + 3];
      f32x4 z4 = sk4[pb0 + 4];
      float y0 = odd ? z2[2] : z2[0];
      float y1 = odd ? z2[3] : z2[1];
      int r0 = (pb0 << 2) - 8;
      int r1 = r0;
      // slots 0..7 (z0, z1): q < p0 < p1 -> (<=, <=)
      #pragma unroll
      for (int e = 0; e < 4; ++e) {
        r0 += (z0[e] <= y0) ? 1 : 0;  r1 += (z0[e] <= y1) ? 1 : 0;
        r0 += (z1[e] <= y0) ? 1 : 0;  r1 += (z1[e] <= y1) ? 1 : 0;
      }
      // slots 8..11 (z2): mixed, selected by `odd`
      r0 += (odd && (z2[0] <= y0)) ? 1 : 0;
      r1 += (z2[0] <= y1) ? 1 : 0;
      r0 += (odd ? (z2[1] <= y0) : (z2[1] < y0)) ? 1 : 0;
      r1 += (odd && (z2[1] <= y1)) ? 1 : 0;
      r0 += (!odd && (z2[2] < y0)) ? 1 : 0;
      r1 += (odd ? (z2[2] <= y1) : (z2[2] < y1)) ? 1 : 0;
      r0 += (z2[3] < y0) ? 1 : 0;
      r1 += (!odd && (z2[3] < y1)) ? 1 : 0;
      // slots 12..19 (z3, z4): q > p1 > p0 -> (<, <)
      #pragma unroll
      for (int e = 0; e < 4; ++e) {
        r0 += (z3[e] < y0) ? 1 : 0;  r1 += (z3[e] < y1) ? 1 : 0;
        r0 += (z4[e] < y0) ? 1 : 0;  r1 += (z4[e] < y1) ? 1 : 0;
      }
      acc += y0 * vrow[r0] + y1 * vrow[r1];
    }
  } else {
    // SLOW PATH (block-uniform, ~0.5% of blocks): r11-style segment scan.
    const f32x4* sk4r = (const f32x4*)sk;  // sk is 32B-aligned (skey+8 floats)
    #pragma unroll
    for (int k = 0; k < EL; ++k) {
      int p = tid + NT * k;
      float y = sk[p];
      int b = gbin(y);
      int lo_ = pref[swz(b)];
      int hi_ = (b == NB - 1) ? Nc : pref[swz(b + 1)];
      int q4 = lo_ >> 2;
      int e4 = (hi_ + 3) >> 2;
      int r = q4 << 2;
      for (; q4 < e4; ++q4) {
        f32x4 z = sk4r[q4];
        int qb = q4 << 2;
        r += (z[0] < y || (z[0] == y && qb + 0 < p)) ? 1 : 0;
        r += (z[1] < y || (z[1] == y && qb + 1 < p)) ? 1 : 0;
        r += (z[2] < y || (z[2] == y && qb + 2 < p)) ? 1 : 0;
        r += (z[3] < y || (z[3] == y && qb + 3 < p)) ? 1 : 0;
      }
      acc += y * vrow[r];
    }
  }

  #pragma unroll
  for (int off = 1; off < 64; off <<= 1) acc += __shfl_xor(acc, off, 64);
  __syncthreads();  // all pref reads done before red (aliased) is written
  if ((tid & 63) == 0) red[tid >> 6] = acc;
  __syncthreads();
  if (tid == 0) {
    float t = 0.f;
    #pragma unroll
    for (int ww = 0; ww < 8; ++ww) t += red[ww];
    int b = b0 + bloc;
    out[(size_t)b * Lc + l] = C[l] - t;
  }
}

// ---------------------------------------------------------------------------
extern "C" void kernel_launch(void* const* d_in, const int* in_sizes, int n_in,
                              void* d_out, int out_size, void* d_ws, size_t ws_size,
                              hipStream_t stream) {
  const float* X       = (const float*)d_in[0];  // [B,N,D]
  const float* theta_v = (const float*)d_in[1];  // [L,D]
  const float* ref     = (const float*)d_in[2];  // [M,L]
  const float* weight  = (const float*)d_in[3];  // [L,M]
  float* out = (float*)d_out;                    // [B,L]

  // workspace layout: v [L*N] f32 | Wh,Wl [L*D] u16 | C [128] f32 | sl f32
  float* v  = (float*)d_ws;
  unsigned short* Wh = (unsigned short*)(v + (size_t)Lc * Nc);
  unsigned short* Wl = Wh + (size_t)Lc * Dc;
  float* Cc = (float*)(Wl + (size_t)Lc * Dc);
  float* sl = Cc + 128;
  size_t used = (size_t)((char*)sl - (char*)d_ws);
  size_t per_b = (size_t)Lc * Nc * sizeof(float);  // 2 MB per batch element
  int chunk = 1;
  if (ws_size > used + per_b) {
    size_t c = (ws_size - used) / per_b;
    chunk = (int)(c > (size_t)Bc ? (size_t)Bc : c);
    if (chunk < 1) chunk = 1;
  }

  setup_kernel<<<Lc, 256, 0, stream>>>(theta_v, ref, weight, Wh, Wl, Cc, v);

  for (int b0 = 0; b0 < Bc; b0 += chunk) {
    int nb = (Bc - b0) < chunk ? (Bc - b0) : chunk;
    dim3 g1(Nc / 128, nb);
    gemm_kernel<<<g1, 512, 0, stream>>>(X + (size_t)b0 * Nc * Dc, Wh, Wl, sl);
    rank_dot_kernel<<<(size_t)nb * Lc, 512, 0, stream>>>(sl, v, Cc, out, b0);
  }
}

// Round 16
// 150.240 us; speedup vs baseline: 1.0581x; 1.0006x over previous
//
#include <hip/hip_runtime.h>
#include <math.h>

// Problem constants
static constexpr int Bc = 64;     // batch
static constexpr int Nc = 4096;   // set size
static constexpr int Dc = 128;    // d_in
static constexpr int Mc = 1024;   // num ref points
static constexpr int Lc = 128;    // num projections

using short8   = __attribute__((ext_vector_type(8))) short;
using ushort8v = __attribute__((ext_vector_type(8))) unsigned short;
using f32x4    = __attribute__((ext_vector_type(4))) float;

__device__ __forceinline__ unsigned short f2bf(float x) {
  unsigned u = __builtin_bit_cast(unsigned, x);
  return (unsigned short)((u + 0x7FFFu + ((u >> 16) & 1u)) >> 16);
}
__device__ __forceinline__ float bf2f(unsigned short h) {
  unsigned u = ((unsigned)h) << 16;
  return __builtin_bit_cast(float, u);
}

__device__ __forceinline__ int swz(int i) { return i ^ ((i >> 4) & 31); }

// ---------------------------------------------------------------------------
// Kernel 1 (setup): per l-block (128 blocks x 256 threads):
//   - Wh/Wl[l][d] = bf16 hi/lo split of theta_v[l]/||theta_v[l]||
//   - C[l] = sum_m ref[m,l]*weight[l,m]
//   - v[l][n]: binning-rank argsort of ref column + interp stencil scatter
// ---------------------------------------------------------------------------
__global__ __launch_bounds__(256) void setup_kernel(
    const float* __restrict__ theta_v, const float* __restrict__ ref,
    const float* __restrict__ weight, unsigned short* __restrict__ Wh,
    unsigned short* __restrict__ Wl, float* __restrict__ C,
    float* __restrict__ v) {
  constexpr int NBv = 2048;
  constexpr float LOv = -4.2f;
  constexpr float SCv = (float)NBv / 8.4f;

  __shared__ int pref[NBv];            // 8 KB
  __shared__ float skey[Mc];           // 4 KB
  __shared__ unsigned short sidx[Mc];  // 2 KB
  __shared__ float vrow[Nc];           // 16 KB
  __shared__ int wsum[4];
  __shared__ float s2[2];
  __shared__ float c4[4];

  int l = blockIdx.x;
  int tid = threadIdx.x;
  int lane = tid & 63, wv = tid >> 6;

  // ref column (also reused for C)
  float x[4];
  #pragma unroll
  for (int j = 0; j < 4; ++j) x[j] = ref[(size_t)(tid + 256 * j) * Lc + l];

  for (int i = tid; i < NBv; i += 256) pref[i] = 0;
  for (int i = tid; i < Nc; i += 256) vrow[i] = 0.f;

  // W-norm partial (threads 0..127; waves 0,1)
  float wval = 0.f;
  if (tid < Dc) {
    wval = theta_v[l * Dc + tid];
    float sq = wval * wval;
    #pragma unroll
    for (int off = 1; off < 64; off <<= 1) sq += __shfl_xor(sq, off, 64);
    if (lane == 0) s2[wv] = sq;
  }
  // C partial (all threads, reuses x)
  {
    float cacc = 0.f;
    #pragma unroll
    for (int j = 0; j < 4; ++j) cacc += x[j] * weight[(size_t)l * Mc + tid + 256 * j];
    #pragma unroll
    for (int off = 1; off < 64; off <<= 1) cacc += __shfl_xor(cacc, off, 64);
    if (lane == 0) c4[wv] = cacc;
  }
  __syncthreads();

  if (tid < Dc) {
    float norm = sqrtf(s2[0] + s2[1]);
    float val = wval / norm;
    unsigned short hi = f2bf(val);
    Wh[l * Dc + tid] = hi;
    Wl[l * Dc + tid] = f2bf(val - bf2f(hi));
  }
  if (tid == 0) C[l] = c4[0] + c4[1] + c4[2] + c4[3];

  // histogram
  int bb[4];
  #pragma unroll
  for (int j = 0; j < 4; ++j) {
    int bi = (int)((x[j] - LOv) * SCv);
    bi = bi < 0 ? 0 : (bi > NBv - 1 ? NBv - 1 : bi);
    bb[j] = bi;
    atomicAdd(&pref[swz(bi)], 1);
  }
  __syncthreads();

  // exclusive prefix over 2048 bins (8/thread)
  {
    int base_ = tid * 8;
    int loc[8]; int s = 0;
    #pragma unroll
    for (int j = 0; j < 8; ++j) loc[j] = pref[swz(base_ + j)];
    #pragma unroll
    for (int j = 0; j < 8; ++j) { int c = loc[j]; loc[j] = s; s += c; }
    int inc = s;
    #pragma unroll
    for (int off = 1; off < 64; off <<= 1) {
      int o = __shfl_up(inc, off, 64);
      if (lane >= off) inc += o;
    }
    if (lane == 63) wsum[wv] = inc;
    __syncthreads();
    int wbase = 0;
    #pragma unroll
    for (int ww = 0; ww < 4; ++ww) if (ww < wv) wbase += wsum[ww];
    int tbase = wbase + inc - s;
    #pragma unroll
    for (int j = 0; j < 8; ++j) pref[swz(base_ + j)] = tbase + loc[j];
  }
  __syncthreads();

  // scatter (value, orig idx)
  #pragma unroll
  for (int j = 0; j < 4; ++j) {
    int p = atomicAdd(&pref[swz(bb[j])], 1);
    skey[p] = x[j];
    sidx[p] = (unsigned short)(tid + 256 * j);
  }
  __syncthreads();

  // position-ordered exact rank (stable: (value, orig idx)) + stencil scatter
  #pragma unroll
  for (int k = 0; k < 4; ++k) {
    int p = tid + 256 * k;
    float y = skey[p];
    int m = sidx[p];
    int b = (int)((y - LOv) * SCv);
    b = b < 0 ? 0 : (b > NBv - 1 ? NBv - 1 : b);
    int lo_ = b ? pref[swz(b - 1)] : 0;
    int hi_ = pref[swz(b)];
    int r = lo_;
    for (int q = lo_; q < hi_; ++q) {
      float z = skey[q];
      r += (z < y || (z == y && sidx[q] < m)) ? 1 : 0;
    }
    // element with original index m has rank r in the stable argsort
    float wvv = weight[(size_t)l * Mc + r];
    double pos = (double)(m + 1) * (double)(Nc + 1) / (double)(Mc + 1) - 1.0;
    int i0 = (int)pos;
    float t = (float)(pos - (double)i0);
    atomicAdd(&vrow[i0], (1.0f - t) * wvv);
    atomicAdd(&vrow[i0 + 1], t * wvv);
  }
  __syncthreads();
  for (int i = tid; i < Nc; i += 256) v[(size_t)l * Nc + i] = vrow[i];
}

// ---------------------------------------------------------------------------
// Kernel 2: MFMA GEMM, f32 = bf16 hi + lo (3-term). f32 output.
//  512 threads = 8 waves; wave wv owns 16 n-rows x 128 l.
// sl[bloc][l][n] = sum_d X[bloc,n,d] * W[l,d]
// ---------------------------------------------------------------------------
__global__ __launch_bounds__(512) void gemm_kernel(
    const float* __restrict__ X, const unsigned short* __restrict__ Whp,
    const unsigned short* __restrict__ Wlp, float* __restrict__ sl) {
  __shared__ unsigned short Bh[2][128][40];  // 20 KB
  __shared__ unsigned short Bl[2][128][40];  // 20 KB

  int bloc = blockIdx.y;
  int nbase = blockIdx.x * 128;
  int tid = threadIdx.x;
  int lane = tid & 63;
  int wv = tid >> 6;       // wave 0..7 -> 16 n-rows each
  int m16 = lane & 15;
  int kg = lane >> 4;

  // B staging: one 8-u16 segment per thread per array
  int brow = tid >> 2;
  int bc = (tid & 3) * 8;
  const unsigned short* gbh = Whp + (size_t)brow * Dc + bc;
  const unsigned short* gbl = Wlp + (size_t)brow * Dc + bc;

  // ---- A: full kg-slice of the lane's row, all 4 chunks, up-front
  const float* arow = X + ((size_t)bloc * Nc + nbase + wv * 16 + m16) * Dc + kg * 8;
  float4 af[4][2];
  #pragma unroll
  for (int c = 0; c < 4; ++c) {
    af[c][0] = *(const float4*)(arow + c * 32);
    af[c][1] = *(const float4*)(arow + c * 32 + 4);
  }

  // prologue: B chunk 0 -> buf0; B chunk 1 -> regs
  ushort8v rbh = *(const ushort8v*)gbh;
  ushort8v rbl = *(const ushort8v*)gbl;
  *(ushort8v*)&Bh[0][brow][bc] = rbh;
  *(ushort8v*)&Bl[0][brow][bc] = rbl;
  rbh = *(const ushort8v*)(gbh + 32);
  rbl = *(const ushort8v*)(gbl + 32);

  f32x4 acc[8] = {};
  __syncthreads();  // buf0 visible

  #pragma unroll
  for (int c = 0; c < 4; ++c) {
    if (c < 3) {
      *(ushort8v*)&Bh[(c + 1) & 1][brow][bc] = rbh;
      *(ushort8v*)&Bl[(c + 1) & 1][brow][bc] = rbl;
    }
    if (c < 2) {
      rbh = *(const ushort8v*)(gbh + (c + 2) * 32);
      rbl = *(const ushort8v*)(gbl + (c + 2) * 32);
    }

    // convert A chunk c
    float xs[8] = {af[c][0].x, af[c][0].y, af[c][0].z, af[c][0].w,
                   af[c][1].x, af[c][1].y, af[c][1].z, af[c][1].w};
    short8 ah, al;
    #pragma unroll
    for (int e = 0; e < 8; ++e) {
      unsigned short h = f2bf(xs[e]);
      ah[e] = (short)h;
      al[e] = (short)f2bf(xs[e] - bf2f(h));
    }

    #pragma unroll
    for (int u = 0; u < 8; ++u) {
      short8 bh = *(const short8*)&Bh[c & 1][u * 16 + m16][kg * 8];
      short8 bl = *(const short8*)&Bl[c & 1][u * 16 + m16][kg * 8];
      acc[u] = __builtin_amdgcn_mfma_f32_16x16x32_bf16(ah, bh, acc[u], 0, 0, 0);
      acc[u] = __builtin_amdgcn_mfma_f32_16x16x32_bf16(ah, bl, acc[u], 0, 0, 0);
      acc[u] = __builtin_amdgcn_mfma_f32_16x16x32_bf16(al, bh, acc[u], 0, 0, 0);
    }
    __syncthreads();
  }

  // write-out: C/D col = m16 (l), row = kg*4 + reg (n)
  #pragma unroll
  for (int u = 0; u < 8; ++u) {
    int l = u * 16 + m16;
    int n0 = nbase + wv * 16 + kg * 4;
    float* dst = sl + ((size_t)bloc * Lc + l) * Nc + n0;
    *(float4*)dst = *(float4*)&acc[u];
  }
}

// ---------------------------------------------------------------------------
// Kernel 3 (v13): radix-bin + QUAD fixed-window rank + fused dot.
//  Thread handles 4 consecutive positions 4q..4q+3 per step; the 5 aligned
//  float4 blocks skey[q..q+4] serve ALL FOUR elements:
//    - 10 ds_read_b128 per thread total (was 20 with pairs)
//    - intra-quad comparisons have compile-time position signs (no selects)
//    - base = 4q-8 cancels the 8 front -INF sentinels exactly
//  Guard c<=8 unchanged (window covers +-8 for each e); fallback unchanged.
// ---------------------------------------------------------------------------
__device__ __forceinline__ int gbin(float x) {
  constexpr int NB = 4096;
  // NB / (1 + exp(-1.702 x)) = NB / (1 + exp2(-2.45541 x))  (monotone)
  float t = __builtin_amdgcn_exp2f(x * -2.45541f);
  float r = __builtin_amdgcn_rcpf(1.0f + t);
  int bi = (int)((float)NB * r);
  return bi < 0 ? 0 : (bi > NB - 1 ? NB - 1 : bi);
}

__global__ __launch_bounds__(512, 8) void rank_dot_kernel(
    const float* __restrict__ sl, const float* __restrict__ v,
    const float* __restrict__ C, float* __restrict__ out, int b0) {
  constexpr int NB = 4096;
  constexpr int NT = 512;
  constexpr int EL = Nc / NT;  // 8 elements per thread

  __shared__ int pref[NB];                        // hist -> EXCLUSIVE prefix; then red
  __shared__ __align__(16) float skey[Nc + 16];   // 8 sentinel floats each side
  __shared__ int wsum[8];
  __shared__ int ovf;
  float* red = (float*)pref;     // live only after final barrier
  float* sk = skey + 8;          // real positions 0..Nc-1

  int l = blockIdx.x & (Lc - 1);
  int bloc = blockIdx.x >> 7;
  int tid = threadIdx.x;
  const float* src = sl + ((size_t)bloc * Lc + l) * Nc;

  // coalesced strided load: thread owns float4s {tid + 512*j}
  float x[EL];
  {
    const float4* s4 = (const float4*)src;
    #pragma unroll
    for (int j = 0; j < EL / 4; ++j) {
      float4 f = s4[tid + NT * j];
      x[j * 4 + 0] = f.x; x[j * 4 + 1] = f.y;
      x[j * 4 + 2] = f.z; x[j * 4 + 3] = f.w;
    }
  }

  // init: zero pref (b128), sentinels, ovf
  {
    int4 z = make_int4(0, 0, 0, 0);
    ((int4*)pref)[tid] = z;
    ((int4*)pref)[tid + NT] = z;
  }
  if (tid < 8) skey[tid] = -INFINITY;
  else if (tid < 16) skey[Nc + tid] = INFINITY;  // indices Nc+8 .. Nc+15
  if (tid == 16) ovf = 0;
  __syncthreads();

  // histogram; returned old count = within-bin slot; slot>=8 -> bin c>=9
  int bb[EL];
  int ofs[EL];
  bool myovf = false;
  #pragma unroll
  for (int j = 0; j < EL; ++j) {
    int bi = gbin(x[j]);
    bb[j] = bi;
    ofs[j] = atomicAdd(&pref[swz(bi)], 1);
    myovf |= (ofs[j] >= 8);
  }
  if (myovf) ovf = 1;
  __syncthreads();

  // exclusive prefix sum over 4096 bins (8 bins/thread)
  {
    int base_ = tid * 8;
    int loc[8]; int s = 0;
    #pragma unroll
    for (int j = 0; j < 8; ++j) loc[j] = pref[swz(base_ + j)];
    #pragma unroll
    for (int j = 0; j < 8; ++j) { int c = loc[j]; loc[j] = s; s += c; }
    int lane = tid & 63, wvv = tid >> 6;
    int inc = s;
    #pragma unroll
    for (int off = 1; off < 64; off <<= 1) {
      int o = __shfl_up(inc, off, 64);
      if (lane >= off) inc += o;
    }
    if (lane == 63) wsum[wvv] = inc;
    __syncthreads();
    int wbase = 0;
    #pragma unroll
    for (int ww = 0; ww < 8; ++ww) if (ww < wvv) wbase += wsum[ww];
    int tbase = wbase + inc - s;  // exclusive across threads
    #pragma unroll
    for (int j = 0; j < 8; ++j) pref[swz(base_ + j)] = tbase + loc[j];
  }
  __syncthreads();

  // scatter: pos = exclusive-prefix + slot (no second atomic; pref unchanged)
  #pragma unroll
  for (int j = 0; j < EL; ++j) {
    sk[pref[swz(bb[j])] + ofs[j]] = x[j];
  }
  __syncthreads();

  const float* vrow = v + (size_t)l * Nc;
  float acc = 0.f;

  if (__builtin_expect(ovf == 0, 1)) {
    // FAST PATH: quad fixed-window. Quad q covers real positions 4q..4q+3
    // (= skey block q+2); window = skey blocks q..q+4. Cells below window
    // are in earlier bins (counted via base, sentinel offset -8); above in
    // later bins (never counted). Within window: position-sign is
    // compile-time for all slots (own block = intra-quad pairs).
    const f32x4* sk4 = (const f32x4*)skey;
    #pragma unroll
    for (int k = 0; k < 2; ++k) {
      int q = tid + NT * k;     // quad index 0..1023
      f32x4 z0 = sk4[q + 0];
      f32x4 z1 = sk4[q + 1];
      f32x4 z2 = sk4[q + 2];    // own 4 elements
      f32x4 z3 = sk4[q + 3];
      f32x4 z4 = sk4[q + 4];
      int base = (q << 2) - 8;
      float y0 = z2[0], y1 = z2[1], y2 = z2[2], y3 = z2[3];
      int r0 = base, r1 = base, r2 = base, r3 = base;
      #pragma unroll
      for (int e = 0; e < 4; ++e) {
        float za = z0[e], zb = z1[e], zc = z3[e], zd = z4[e];
        r0 += (za <= y0) ? 1 : 0;  r1 += (za <= y1) ? 1 : 0;
        r2 += (za <= y2) ? 1 : 0;  r3 += (za <= y3) ? 1 : 0;
        r0 += (zb <= y0) ? 1 : 0;  r1 += (zb <= y1) ? 1 : 0;
        r2 += (zb <= y2) ? 1 : 0;  r3 += (zb <= y3) ? 1 : 0;
        r0 += (zc < y0) ? 1 : 0;   r1 += (zc < y1) ? 1 : 0;
        r2 += (zc < y2) ? 1 : 0;   r3 += (zc < y3) ? 1 : 0;
        r0 += (zd < y0) ? 1 : 0;   r1 += (zd < y1) ? 1 : 0;
        r2 += (zd < y2) ? 1 : 0;   r3 += (zd < y3) ? 1 : 0;
      }
      // intra-quad (positions 4q+0 < 4q+1 < 4q+2 < 4q+3):
      r1 += (y0 <= y1) ? 1 : 0;
      r2 += (y0 <= y2) ? 1 : 0;  r2 += (y1 <= y2) ? 1 : 0;
      r3 += (y0 <= y3) ? 1 : 0;  r3 += (y1 <= y3) ? 1 : 0;  r3 += (y2 <= y3) ? 1 : 0;
      r0 += (y1 < y0) ? 1 : 0;   r0 += (y2 < y0) ? 1 : 0;   r0 += (y3 < y0) ? 1 : 0;
      r1 += (y2 < y1) ? 1 : 0;   r1 += (y3 < y1) ? 1 : 0;
      r2 += (y3 < y2) ? 1 : 0;
      acc += y0 * vrow[r0] + y1 * vrow[r1] + y2 * vrow[r2] + y3 * vrow[r3];
    }
  } else {
    // SLOW PATH (block-uniform, ~0.5% of blocks): segment scan.
    const f32x4* sk4r = (const f32x4*)sk;  // sk is 32B-aligned (skey+8 floats)
    #pragma unroll
    for (int k = 0; k < EL; ++k) {
      int p = tid + NT * k;
      float y = sk[p];
      int b = gbin(y);
      int lo_ = pref[swz(b)];
      int hi_ = (b == NB - 1) ? Nc : pref[swz(b + 1)];
      int q4 = lo_ >> 2;
      int e4 = (hi_ + 3) >> 2;
      int r = q4 << 2;
      for (; q4 < e4; ++q4) {
        f32x4 z = sk4r[q4];
        int qb = q4 << 2;
        r += (z[0] < y || (z[0] == y && qb + 0 < p)) ? 1 : 0;
        r += (z[1] < y || (z[1] == y && qb + 1 < p)) ? 1 : 0;
        r += (z[2] < y || (z[2] == y && qb + 2 < p)) ? 1 : 0;
        r += (z[3] < y || (z[3] == y && qb + 3 < p)) ? 1 : 0;
      }
      acc += y * vrow[r];
    }
  }

  #pragma unroll
  for (int off = 1; off < 64; off <<= 1) acc += __shfl_xor(acc, off, 64);
  __syncthreads();  // all pref reads done before red (aliased) is written
  if ((tid & 63) == 0) red[tid >> 6] = acc;
  __syncthreads();
  if (tid == 0) {
    float t = 0.f;
    #pragma unroll
    for (int ww = 0; ww < 8; ++ww) t += red[ww];
    int b = b0 + bloc;
    out[(size_t)b * Lc + l] = C[l] - t;
  }
}

// ---------------------------------------------------------------------------
extern "C" void kernel_launch(void* const* d_in, const int* in_sizes, int n_in,
                              void* d_out, int out_size, void* d_ws, size_t ws_size,
                              hipStream_t stream) {
  const float* X       = (const float*)d_in[0];  // [B,N,D]
  const float* theta_v = (const float*)d_in[1];  // [L,D]
  const float* ref     = (const float*)d_in[2];  // [M,L]
  const float* weight  = (const float*)d_in[3];  // [L,M]
  float* out = (float*)d_out;                    // [B,L]

  // workspace layout: v [L*N] f32 | Wh,Wl [L*D] u16 | C [128] f32 | sl f32
  float* v  = (float*)d_ws;
  unsigned short* Wh = (unsigned short*)(v + (size_t)Lc * Nc);
  unsigned short* Wl = Wh + (size_t)Lc * Dc;
  float* Cc = (float*)(Wl + (size_t)Lc * Dc);
  float* sl = Cc + 128;
  size_t used = (size_t)((char*)sl - (char*)d_ws);
  size_t per_b = (size_t)Lc * Nc * sizeof(float);  // 2 MB per batch element
  int chunk = 1;
  if (ws_size > used + per_b) {
    size_t c = (ws_size - used) / per_b;
    chunk = (int)(c > (size_t)Bc ? (size_t)Bc : c);
    if (chunk < 1) chunk = 1;
  }

  setup_kernel<<<Lc, 256, 0, stream>>>(theta_v, ref, weight, Wh, Wl, Cc, v);

  for (int b0 = 0; b0 < Bc; b0 += chunk) {
    int nb = (Bc - b0) < chunk ? (Bc - b0) : chunk;
    dim3 g1(Nc / 128, nb);
    gemm_kernel<<<g1, 512, 0, stream>>>(X + (size_t)b0 * Nc * Dc, Wh, Wl, sl);
    rank_dot_kernel<<<(size_t)nb * Lc, 512, 0, stream>>>(sl, v, Cc, out, b0);
  }
}